// Round 10
// baseline (395.363 us; speedup 1.0000x reference)
//
#include <hip/hip_runtime.h>
#include <hip/hip_bf16.h>
#include <stdint.h>

typedef __bf16 bf16;
typedef __attribute__((ext_vector_type(8))) __bf16 bf16x8;
typedef __attribute__((ext_vector_type(4))) __bf16 bf16x4;
typedef __attribute__((ext_vector_type(4))) float f32x4;

// async global->LDS, 16B per lane. LDS dest is linear: wave base + lane*16.
#define GLD(g, l) __builtin_amdgcn_global_load_lds( \
    (const __attribute__((address_space(1))) void*)(g), \
    (__attribute__((address_space(3))) void*)(l), 16, 0, 0)

__device__ __forceinline__ f32x4 mfma16(bf16x8 a, bf16x8 b, f32x4 c) {
  return __builtin_amdgcn_mfma_f32_16x16x32_bf16(a, b, c, 0, 0, 0);
}
__device__ __forceinline__ float fexp2(float x) {
  return __builtin_amdgcn_exp2f(x);
}

// ---------------------------------------------------------------------------
// Fused per-head weight transpose: W{q,k,v}[h][1024 d][64 e](fp32) ->
// WT[w][(h*64+e)][d](bf16). grid (32,32,3), block (32,8).
// ---------------------------------------------------------------------------
__global__ void wtrans3(const float* __restrict__ Wq, const float* __restrict__ Wk,
                        const float* __restrict__ Wv, bf16* __restrict__ WT)
{
  __shared__ bf16 t[32][33];
  const int w = blockIdx.z;
  const float* W = (w == 0) ? Wq : (w == 1) ? Wk : Wv;
  const int h = blockIdx.x >> 1;
  const int c0 = (blockIdx.x & 1) * 32;
  const int r0 = blockIdx.y * 32;
  const float* s = W + (size_t)h * 65536;
  bf16* d = WT + (size_t)w * (1 << 20) + (size_t)h * 65536;
  const int tx = threadIdx.x, ty = threadIdx.y;
#pragma unroll
  for (int i = 0; i < 32; i += 8)
    t[ty + i][tx] = (bf16)s[(r0 + ty + i) * 64 + c0 + tx];
  __syncthreads();
#pragma unroll
  for (int i = 0; i < 32; i += 8)
    d[(c0 + ty + i) * 1024 + r0 + tx] = t[tx][ty + i];
}

// ---------------------------------------------------------------------------
// Wo[k,n](fp32) -> WoT[n,k](bf16). grid (32,32), block (32,8).
// ---------------------------------------------------------------------------
__global__ void wtransO(const float* __restrict__ src, bf16* __restrict__ dst)
{
  __shared__ bf16 t[32][33];
  const int c0 = blockIdx.x * 32, r0 = blockIdx.y * 32;
  const int tx = threadIdx.x, ty = threadIdx.y;
#pragma unroll
  for (int i = 0; i < 32; i += 8)
    t[ty + i][tx] = (bf16)src[(r0 + ty + i) * 1024 + c0 + tx];
  __syncthreads();
#pragma unroll
  for (int i = 0; i < 32; i += 8)
    dst[(c0 + ty + i) * 1024 + r0 + tx] = t[tx][ty + i];
}

// ---------------------------------------------------------------------------
// Fused QKV projection, stacked-M (seg = q/k/v). 128x128 tile, BK=32.
// A: fp32 direct (no cast pass) reg-prefetch -> cvt -> PADDED LDS (36 el/row,
//    ~2-way bank aliasing = free) double-buffered, ONE barrier/iter.
// B: weights (L2-hot, 2 MB/seg) read PER-WAVE direct global->regs, prefetched
//    one iter ahead — L2 latency (~200cyc) hidden under the compute phase and
//    NOT subject to the barrier's vmcnt(0) drain cost (drained post-compute).
// LDS total 18 KB -> ~3 blocks/CU for cross-block latency overlap.
// grid (192 m-fast, 8 n): same-stripe blocks share XCD for A L2 reuse.
// ---------------------------------------------------------------------------
__global__ __launch_bounds__(256) void proj_qkv(
    const float* __restrict__ Aq, const float* __restrict__ Ak,
    const float* __restrict__ Av, const bf16* __restrict__ WT,
    const float* __restrict__ bq, const float* __restrict__ bk,
    const float* __restrict__ bv, bf16* __restrict__ qh,
    bf16* __restrict__ kh, bf16* __restrict__ vt, float cscale)
{
  __shared__ bf16 sA[2][128 * 36];   // padded rows
  const int tid = threadIdx.x;
  const int wave = tid >> 6, lane = tid & 63;
  const int lr = lane & 15, quad = lane >> 4, kq = quad * 8;
  const int n0 = blockIdx.y * 128;
  const int mseg = blockIdx.x * 128;
  const int seg = mseg >> 13;
  const int m0 = mseg & 8191;
  const int wr = (wave >> 1) * 64, wc = (wave & 1) * 64;

  const float* A = (seg == 0) ? Aq : (seg == 1) ? Ak : Av;
  const float* bias = (seg == 0) ? bq : (seg == 1) ? bk : bv;
  const bf16* Bt = WT + (size_t)seg * (1 << 20);

  f32x4 acc[4][4];
#pragma unroll
  for (int i = 0; i < 4; i++)
#pragma unroll
    for (int j = 0; j < 4; j++)
#pragma unroll
      for (int e = 0; e < 4; e++) acc[i][j][e] = 0.f;

  // A: row = tid>>1 (0..127), 16 fp32 cols at (tid&1)*16
  const int ar = tid >> 1, ac = (tid & 1) * 16;
  const float* aPtr = A + (size_t)(m0 + ar) * 1024 + ac;
  // B: per-wave direct; frag i row = n0+wc+i*16+lr, k-cols kq..kq+8
  const bf16* bRow = Bt + (size_t)(n0 + wc + lr) * 1024 + kq;

  float4 f[4];
#pragma unroll
  for (int j = 0; j < 4; j++) f[j] = *(const float4*)(aPtr + j * 4);
  {  // cvt+store tile 0 into buf 0 (visible after first barrier)
    bf16x8 p0, p1;
    p0[0]=(bf16)f[0].x; p0[1]=(bf16)f[0].y; p0[2]=(bf16)f[0].z; p0[3]=(bf16)f[0].w;
    p0[4]=(bf16)f[1].x; p0[5]=(bf16)f[1].y; p0[6]=(bf16)f[1].z; p0[7]=(bf16)f[1].w;
    p1[0]=(bf16)f[2].x; p1[1]=(bf16)f[2].y; p1[2]=(bf16)f[2].z; p1[3]=(bf16)f[2].w;
    p1[4]=(bf16)f[3].x; p1[5]=(bf16)f[3].y; p1[6]=(bf16)f[3].z; p1[7]=(bf16)f[3].w;
    *(bf16x8*)(&sA[0][ar * 36 + ac])     = p0;
    *(bf16x8*)(&sA[0][ar * 36 + ac + 8]) = p1;
  }
  bf16x8 bfr[4], bnx[4];
#pragma unroll
  for (int i = 0; i < 4; i++) bfr[i] = *(const bf16x8*)(bRow + i * 16384);
#pragma unroll
  for (int j = 0; j < 4; j++) f[j] = *(const float4*)(aPtr + 32 + j * 4);

  for (int it = 0; it < 32; ++it) {
    const int p = it & 1;
    __syncthreads();  // sA[p] stores visible; outstanding loads drained
    const bool more = (it + 1 < 32);
    if (more) {
      const int kn = (it + 1) * 32;
#pragma unroll
      for (int i = 0; i < 4; i++)
        bnx[i] = *(const bf16x8*)(bRow + i * 16384 + kn);
    }
    bf16x8 af[4];
#pragma unroll
    for (int i = 0; i < 4; i++)
      af[i] = *(const bf16x8*)(&sA[p][(wr + i * 16 + lr) * 36 + kq]);
#pragma unroll
    for (int im = 0; im < 4; im++)
#pragma unroll
      for (int in = 0; in < 4; in++)
        acc[im][in] = mfma16(af[im], bfr[in], acc[im][in]);
    if (more) {
      bf16x8 p0, p1;  // cvt tile it+1 (f flew for ~1 iter) -> buf p^1
      p0[0]=(bf16)f[0].x; p0[1]=(bf16)f[0].y; p0[2]=(bf16)f[0].z; p0[3]=(bf16)f[0].w;
      p0[4]=(bf16)f[1].x; p0[5]=(bf16)f[1].y; p0[6]=(bf16)f[1].z; p0[7]=(bf16)f[1].w;
      p1[0]=(bf16)f[2].x; p1[1]=(bf16)f[2].y; p1[2]=(bf16)f[2].z; p1[3]=(bf16)f[2].w;
      p1[4]=(bf16)f[3].x; p1[5]=(bf16)f[3].y; p1[6]=(bf16)f[3].z; p1[7]=(bf16)f[3].w;
      *(bf16x8*)(&sA[p ^ 1][ar * 36 + ac])     = p0;
      *(bf16x8*)(&sA[p ^ 1][ar * 36 + ac + 8]) = p1;
      if (it + 2 < 32) {
        const int ka = (it + 2) * 32;
#pragma unroll
        for (int j = 0; j < 4; j++) f[j] = *(const float4*)(aPtr + ka + j * 4);
      }
#pragma unroll
      for (int i = 0; i < 4; i++) bfr[i] = bnx[i];
    }
  }

  const int qd = quad * 4;
  float bv4[4];
#pragma unroll
  for (int in = 0; in < 4; in++) bv4[in] = bias[n0 + wc + in * 16 + lr];

  if (seg < 2) {
    bf16* C = (seg == 0) ? qh : kh;
    const float cmul = (seg == 0) ? cscale : 1.0f;
#pragma unroll
    for (int im = 0; im < 4; im++) {
      const int row = m0 + wr + im * 16 + qd;
#pragma unroll
      for (int in = 0; in < 4; in++) {
        const int col = n0 + wc + in * 16 + lr;
#pragma unroll
        for (int i = 0; i < 4; i++)
          C[(size_t)(row + i) * 1024 + col] = (bf16)((acc[im][in][i] + bv4[in]) * cmul);
      }
    }
  } else {
#pragma unroll
    for (int im = 0; im < 4; im++) {
      const int row = m0 + wr + im * 16 + qd;
      const int b = row >> 10, sin = row & 1023;
#pragma unroll
      for (int in = 0; in < 4; in++) {
        const int col = n0 + wc + in * 16 + lr;
        const int h = col >> 6, e = col & 63;
        bf16x4 pk;
#pragma unroll
        for (int i = 0; i < 4; i++) pk[i] = (bf16)(acc[im][in][i] + bv4[in]);
        *(bf16x4*)(vt + (size_t)(b * 16 + h) * 65536 + e * 1024 + sin) = pk;
      }
    }
  }
}

// ---------------------------------------------------------------------------
// Final GEMM: out[8192,1024](fp32) = A(bf16) @ WoT^T + bo. BK=32.
// A via GLD double-buffer (ONE barrier/iter); B (WoT, L2-hot) per-wave
// direct global->regs prefetched one iter ahead. LDS 16 KB.
// grid (64 m-fast, 8 n).
// ---------------------------------------------------------------------------
__global__ __launch_bounds__(256) void gemm_a16_c32(
    const bf16* __restrict__ A, const bf16* __restrict__ Bt,
    const float* __restrict__ bias, float* __restrict__ C)
{
  __shared__ bf16 S[2][4096];
  const int tid = threadIdx.x;
  const int wave = tid >> 6, lane = tid & 63;
  const int lr = lane & 15, quad = lane >> 4, kq = quad * 8;
  const int m0 = blockIdx.x * 128, n0 = blockIdx.y * 128;
  const int wr = (wave >> 1) * 64, wc = (wave & 1) * 64;

  f32x4 acc[4][4];
#pragma unroll
  for (int i = 0; i < 4; i++)
#pragma unroll
    for (int j = 0; j < 4; j++)
#pragma unroll
      for (int e = 0; e < 4; e++) acc[i][j][e] = 0.f;

  const int srow = tid >> 2;
  const int sko = (tid & 3) * 8;
  const bf16* aPtr = A + (size_t)(m0 + srow) * 1024 + sko;
  const bf16* bRow = Bt + (size_t)(n0 + wc + lr) * 1024 + kq;

  GLD(aPtr,             &S[0][tid * 8]);
  GLD(aPtr + 64 * 1024, &S[0][2048 + tid * 8]);
  bf16x8 bfr[4], bnx[4];
#pragma unroll
  for (int i = 0; i < 4; i++) bfr[i] = *(const bf16x8*)(bRow + i * 16384);

  for (int it = 0; it < 32; ++it) {
    const int p = it & 1;
    __syncthreads();
    const bool more = (it + 1 < 32);
    if (more) {
      const int kn = (it + 1) * 32;
      GLD(aPtr + kn,             &S[p ^ 1][tid * 8]);
      GLD(aPtr + 64 * 1024 + kn, &S[p ^ 1][2048 + tid * 8]);
#pragma unroll
      for (int i = 0; i < 4; i++)
        bnx[i] = *(const bf16x8*)(bRow + i * 16384 + kn);
    }
    bf16x8 af[4];
#pragma unroll
    for (int i = 0; i < 4; i++)
      af[i] = *(const bf16x8*)(&S[p][(wr + i * 16 + lr) * 32 + kq]);
#pragma unroll
    for (int im = 0; im < 4; im++)
#pragma unroll
      for (int in = 0; in < 4; in++)
        acc[im][in] = mfma16(af[im], bfr[in], acc[im][in]);
    if (more) {
#pragma unroll
      for (int i = 0; i < 4; i++) bfr[i] = bnx[i];
    }
  }

  const int qd = quad * 4;
  float bv4[4];
#pragma unroll
  for (int in = 0; in < 4; in++) bv4[in] = bias[n0 + wc + in * 16 + lr];
#pragma unroll
  for (int im = 0; im < 4; im++) {
    const int row = m0 + wr + im * 16 + qd;
#pragma unroll
    for (int in = 0; in < 4; in++) {
      const int col = n0 + wc + in * 16 + lr;
#pragma unroll
      for (int i = 0; i < 4; i++)
        C[(size_t)(row + i) * 1024 + col] = acc[im][in][i] + bv4[in];
    }
  }
}

// ---------------------------------------------------------------------------
// Flash attention per (b,h) — unchanged from round 9.
// ---------------------------------------------------------------------------
__global__ __launch_bounds__(256) void attn_k(
    const bf16* Q, const bf16* __restrict__ Kh,
    const bf16* __restrict__ Vt, bf16* O)
{
  __shared__ bf16 sK[64 * 72];
  __shared__ bf16 sV[64 * 72];
  __shared__ bf16 sP[128 * 72];
  const int h = blockIdx.x, b = blockIdx.y, q0 = blockIdx.z * 128;
  const int tid = threadIdx.x, wave = tid >> 6, lane = tid & 63;
  const int lr = lane & 15, quad = lane >> 4, kq = quad * 8;
  const int wq = wave * 32;

  const bf16* Qb = Q + (size_t)(b * 1024 + q0) * 1024 + h * 64;
  const bf16* Kb = Kh + (size_t)(b * 1024) * 1024 + h * 64;
  const bf16* Vb = Vt + (size_t)(b * 16 + h) * 65536;

  bf16x8 qf[2][2];
#pragma unroll
  for (int rg = 0; rg < 2; rg++)
#pragma unroll
    for (int ks = 0; ks < 2; ks++)
      qf[rg][ks] = *(const bf16x8*)(Qb + (wq + rg * 16 + lr) * 1024 + ks * 32 + kq);

  f32x4 o[2][4];
  float rsum[2][4];
#pragma unroll
  for (int rg = 0; rg < 2; rg++) {
#pragma unroll
    for (int et = 0; et < 4; et++)
#pragma unroll
      for (int e = 0; e < 4; e++) o[rg][et][e] = 0.f;
#pragma unroll
    for (int i = 0; i < 4; i++) rsum[rg][i] = 0.f;
  }

  const int r = tid >> 3;
  const int c = (tid & 7) * 8;

  bf16x8 k1 = *(const bf16x8*)(Kb + (size_t)r * 1024 + c);
  bf16x8 k2 = *(const bf16x8*)(Kb + (size_t)(32 + r) * 1024 + c);
  bf16x8 v1 = *(const bf16x8*)(Vb + (size_t)r * 1024 + c);
  bf16x8 v2 = *(const bf16x8*)(Vb + (size_t)(32 + r) * 1024 + c);

  for (int kv0 = 0; kv0 < 1024; kv0 += 64) {
    __syncthreads();
    *(bf16x8*)(sK + r * 72 + c) = k1;
    *(bf16x8*)(sK + (32 + r) * 72 + c) = k2;
    *(bf16x8*)(sV + r * 72 + c) = v1;
    *(bf16x8*)(sV + (32 + r) * 72 + c) = v2;
    __syncthreads();
    if (kv0 + 64 < 1024) {
      k1 = *(const bf16x8*)(Kb + (size_t)(kv0 + 64 + r) * 1024 + c);
      k2 = *(const bf16x8*)(Kb + (size_t)(kv0 + 96 + r) * 1024 + c);
      v1 = *(const bf16x8*)(Vb + (size_t)r * 1024 + kv0 + 64 + c);
      v2 = *(const bf16x8*)(Vb + (size_t)(32 + r) * 1024 + kv0 + 64 + c);
    }

    f32x4 sc[2][4];
#pragma unroll
    for (int nt = 0; nt < 4; nt++) {
      bf16x8 kf0 = *(const bf16x8*)(sK + (nt * 16 + lr) * 72 + kq);
      bf16x8 kf1 = *(const bf16x8*)(sK + (nt * 16 + lr) * 72 + 32 + kq);
#pragma unroll
      for (int rg = 0; rg < 2; rg++) {
        f32x4 z;
#pragma unroll
        for (int e = 0; e < 4; e++) z[e] = 0.f;
        z = mfma16(qf[rg][0], kf0, z);
        z = mfma16(qf[rg][1], kf1, z);
        sc[rg][nt] = z;
      }
    }

#pragma unroll
    for (int rg = 0; rg < 2; rg++)
#pragma unroll
      for (int i = 0; i < 4; i++) {
        float p0 = fexp2(sc[rg][0][i]);
        float p1 = fexp2(sc[rg][1][i]);
        float p2 = fexp2(sc[rg][2][i]);
        float p3 = fexp2(sc[rg][3][i]);
        rsum[rg][i] += (p0 + p1) + (p2 + p3);
        const int prow = (wq + rg * 16 + quad * 4 + i) * 72;
        sP[prow + 0 * 16 + lr] = (bf16)p0;
        sP[prow + 1 * 16 + lr] = (bf16)p1;
        sP[prow + 2 * 16 + lr] = (bf16)p2;
        sP[prow + 3 * 16 + lr] = (bf16)p3;
      }
    __syncthreads();

#pragma unroll
    for (int et = 0; et < 4; et++) {
      bf16x8 vf0 = *(const bf16x8*)(sV + (et * 16 + lr) * 72 + kq);
      bf16x8 vf1 = *(const bf16x8*)(sV + (et * 16 + lr) * 72 + 32 + kq);
#pragma unroll
      for (int rg = 0; rg < 2; rg++) {
        bf16x8 pa = *(const bf16x8*)(sP + (wq + rg * 16 + lr) * 72 + kq);
        bf16x8 pb = *(const bf16x8*)(sP + (wq + rg * 16 + lr) * 72 + 32 + kq);
        o[rg][et] = mfma16(pa, vf0, o[rg][et]);
        o[rg][et] = mfma16(pb, vf1, o[rg][et]);
      }
    }
  }

#pragma unroll
  for (int rg = 0; rg < 2; rg++)
#pragma unroll
    for (int i = 0; i < 4; i++) {
      float rs = rsum[rg][i];
#pragma unroll
      for (int off = 1; off < 16; off <<= 1)
        rs += __shfl_xor(rs, off, 64);
      rsum[rg][i] = 1.f / rs;
    }

  bf16* Ob = O + (size_t)(b * 1024 + q0) * 1024 + h * 64;
#pragma unroll
  for (int rg = 0; rg < 2; rg++)
#pragma unroll
    for (int i = 0; i < 4; i++) {
      const int row = wq + rg * 16 + quad * 4 + i;
#pragma unroll
      for (int et = 0; et < 4; et++)
        Ob[row * 1024 + et * 16 + lr] = (bf16)(o[rg][et][i] * rsum[rg][i]);
    }
}

// ---------------------------------------------------------------------------
extern "C" void kernel_launch(void* const* d_in, const int* in_sizes, int n_in,
                              void* d_out, int out_size, void* d_ws, size_t ws_size,
                              hipStream_t stream)
{
  const float* q  = (const float*)d_in[0];
  const float* k  = (const float*)d_in[1];
  const float* v  = (const float*)d_in[2];
  const float* Wq = (const float*)d_in[3];
  const float* bq = (const float*)d_in[4];
  const float* Wk = (const float*)d_in[5];
  const float* bk = (const float*)d_in[6];
  const float* Wv = (const float*)d_in[7];
  const float* bv = (const float*)d_in[8];
  const float* Wo = (const float*)d_in[9];
  const float* bo = (const float*)d_in[10];
  float* out = (float*)d_out;
  bf16* ws = (bf16*)d_ws;

  const int MB = 1 << 20;
  bf16* WT  = ws;               // [3][1024][1024]
  bf16* qh  = ws + 3 * MB;      // [8192][1024]; attn writes O in-place here
  bf16* kh  = ws + 11 * MB;     // [8192][1024]
  bf16* vt  = ws + 19 * MB;     // [B*H][64 e][1024 s]
  bf16* WoT = ws + 27 * MB;     // [1024][1024]  (ws total 56 MB)

  const float cscale = 0.1803368801111601f;  // (1/8)*log2(e), folded into qh

  dim3 tb(32, 8);
  wtrans3<<<dim3(32, 32, 3), tb, 0, stream>>>(Wq, Wk, Wv, WT);
  wtransO<<<dim3(32, 32), tb, 0, stream>>>(Wo, WoT);

  // fp32-direct fused projections (no cast pass)
  proj_qkv<<<dim3(192, 8), 256, 0, stream>>>(q, k, v, WT, bq, bk, bv,
                                             qh, kh, vt, cscale);

  attn_k<<<dim3(16, 8, 8), 256, 0, stream>>>(qh, kh, vt, qh);

  gemm_a16_c32<<<dim3(64, 8), 256, 0, stream>>>(qh, WoT, bo, out);
}